// Round 1
// baseline (94.876 us; speedup 1.0000x reference)
//
#include <hip/hip_runtime.h>
#include <hip/hip_bf16.h>
#include <math.h>

#define K_DCG 512
// SIGMA == 1.0f is folded into the math (exp(SIGMA*x) == exp(x), leading SIGMA* == *1)

// ---------------------------------------------------------------------------
// Kernel 0: zero the maxDCG accumulator (ws is poisoned 0xAA before each run)
// ---------------------------------------------------------------------------
__global__ void init_kernel(float* __restrict__ maxdcg) {
    if (threadIdx.x == 0) *maxdcg = 0.0f;
}

// ---------------------------------------------------------------------------
// Kernel A: per-element preprocessing.
// One wave (64 lanes) per element i:
//   rank_i = 1 + #{j: t_j < t_i} + #{j < i: t_j == t_i}   (== stable argsort-of-argsort)
//   decay_i = 1/log2(rank_i + 1)
//   gain_i  = 2^t_i
//   ep_i = exp(p_i), em_i = exp(-p_i)
//   maxDCG += (gain_i - 1)/log2(pos_i + 1)  where pos_i = N - rank_i + 1, if pos_i <= 512
// ---------------------------------------------------------------------------
__global__ __launch_bounds__(256) void rank_kernel(
        const float* __restrict__ pred, const float* __restrict__ targ,
        float* __restrict__ decay, float* __restrict__ gain,
        float* __restrict__ ep, float* __restrict__ em,
        float* __restrict__ maxdcg, int N) {
    const int wave = threadIdx.x >> 6;
    const int lane = threadIdx.x & 63;
    const int i = blockIdx.x * 4 + wave;
    if (i >= N) return;

    const float ti = targ[i];
    const float4* t4 = (const float4*)targ;
    const int n4 = N >> 2;

    int cnt = 0;
    for (int j4 = lane; j4 < n4; j4 += 64) {
        float4 t = t4[j4];
        int jb = j4 << 2;
        cnt += (t.x < ti) || (t.x == ti && (jb + 0) < i);
        cnt += (t.y < ti) || (t.y == ti && (jb + 1) < i);
        cnt += (t.z < ti) || (t.z == ti && (jb + 2) < i);
        cnt += (t.w < ti) || (t.w == ti && (jb + 3) < i);
    }
    // wave64 reduction
    #pragma unroll
    for (int off = 32; off; off >>= 1) cnt += __shfl_down(cnt, off, 64);

    if (lane == 0) {
        const float rank = (float)(cnt + 1);
        const float d = 1.0f / log2f(rank + 1.0f);
        const float g = exp2f(ti);
        decay[i] = d;
        gain[i]  = g;
        const float pi = pred[i];
        ep[i] = __expf(pi);
        em[i] = __expf(-pi);
        const int pos = N - cnt;              // N - rank + 1
        const int K = (N < K_DCG) ? N : K_DCG;
        if (pos <= K) {
            atomicAdd(maxdcg, (g - 1.0f) / log2f((float)(pos + 1)));
        }
    }
}

// ---------------------------------------------------------------------------
// Kernel B: pairwise lambda sum.
// lam_ij = (0.5*(1-sign(t_i-t_j)) - 1/(1+exp(p_i-p_j))) * |Ninv*(g_i-g_j)*(d_i-d_j)|
// out[i] = sum_j lam_ij
// Ninv (>0) is hoisted to the final write; 1/(1+exp(p_i-p_j)) = 1/(1+ep_i*em_j).
// Block = 256 threads handles TI=16 consecutive i's (in registers); threads
// sweep j with float4 loads; register accumulators; shuffle+LDS reduction.
// ---------------------------------------------------------------------------
#define TI 16

__device__ __forceinline__ void pair_acc(float gi, float di, float epi,
                                         float gj, float dj, float emj,
                                         float& acc) {
    const float delta = fabsf((gi - gj) * (di - dj));
    const float s = (gi < gj) ? 1.0f : 0.0f;
    const float r = __builtin_amdgcn_rcpf(fmaf(epi, emj, 1.0f));
    acc = fmaf(s - r, delta, acc);
}

__global__ __launch_bounds__(256) void pair_kernel(
        const float* __restrict__ decay, const float* __restrict__ gain,
        const float* __restrict__ ep, const float* __restrict__ em,
        const float* __restrict__ maxdcg, float* __restrict__ out, int N) {
    const int i0 = blockIdx.x * TI;
    const int tid = threadIdx.x;

    float gi[TI], di[TI], epi[TI];
    #pragma unroll
    for (int ii = 0; ii < TI; ii++) {
        gi[ii]  = gain[i0 + ii];
        di[ii]  = decay[i0 + ii];
        epi[ii] = ep[i0 + ii];
    }
    float acc[TI];
    #pragma unroll
    for (int ii = 0; ii < TI; ii++) acc[ii] = 0.0f;

    const float4* g4  = (const float4*)gain;
    const float4* d4  = (const float4*)decay;
    const float4* em4 = (const float4*)em;
    const int n4 = N >> 2;

    for (int j4 = tid; j4 < n4; j4 += 256) {
        const float4 gj  = g4[j4];
        const float4 dj  = d4[j4];
        const float4 emj = em4[j4];
        #pragma unroll
        for (int ii = 0; ii < TI; ii++) {
            pair_acc(gi[ii], di[ii], epi[ii], gj.x, dj.x, emj.x, acc[ii]);
            pair_acc(gi[ii], di[ii], epi[ii], gj.y, dj.y, emj.y, acc[ii]);
            pair_acc(gi[ii], di[ii], epi[ii], gj.z, dj.z, emj.z, acc[ii]);
            pair_acc(gi[ii], di[ii], epi[ii], gj.w, dj.w, emj.w, acc[ii]);
        }
    }

    // Reduce 256 threads -> 1 value per ii.
    __shared__ float red[4][TI];
    const int wave = tid >> 6;
    const int lane = tid & 63;
    #pragma unroll
    for (int ii = 0; ii < TI; ii++) {
        float v = acc[ii];
        #pragma unroll
        for (int off = 32; off; off >>= 1) v += __shfl_down(v, off, 64);
        if (lane == 0) red[wave][ii] = v;
    }
    __syncthreads();
    if (tid < TI) {
        const float s = red[0][tid] + red[1][tid] + red[2][tid] + red[3][tid];
        out[i0 + tid] = s / (*maxdcg);   // apply Ninv once
    }
}

// ---------------------------------------------------------------------------
extern "C" void kernel_launch(void* const* d_in, const int* in_sizes, int n_in,
                              void* d_out, int out_size, void* d_ws, size_t ws_size,
                              hipStream_t stream) {
    const float* pred = (const float*)d_in[0];
    const float* targ = (const float*)d_in[1];
    float* out = (float*)d_out;
    const int N = in_sizes[0];   // 8192

    float* ws      = (float*)d_ws;
    float* maxdcg  = ws;               // 1 float (16-float pad for alignment)
    float* decay   = ws + 16;
    float* gain    = ws + 16 + N;
    float* ep      = ws + 16 + 2 * N;
    float* em      = ws + 16 + 3 * N;

    init_kernel<<<1, 64, 0, stream>>>(maxdcg);
    rank_kernel<<<N / 4, 256, 0, stream>>>(pred, targ, decay, gain, ep, em, maxdcg, N);
    pair_kernel<<<N / TI, 256, 0, stream>>>(decay, gain, ep, em, maxdcg, out, N);
}